// Round 7
// baseline (233.799 us; speedup 1.0000x reference)
//
#include <hip/hip_runtime.h>
#include <float.h>

#define N_NODES 4096
#define IN_FEAT 256
#define N_HEADS 8
#define N_HIDDEN 64
#define OUT_FEAT (N_HEADS * N_HIDDEN)  // 512
#define NEG_SLOPE 0.2f
#define KC 128                          // GEMM K-chunk

typedef _Float16 half8 __attribute__((ext_vector_type(8)));
typedef float floatx4 __attribute__((ext_vector_type(4)));

// Monotone float<->uint key for atomicMax-based float max (handles negatives).
__device__ inline unsigned fkey(float f) {
  unsigned u = __float_as_uint(f);
  return (u & 0x80000000u) ? ~u : (u | 0x80000000u);
}
__device__ inline float fkey_inv(unsigned k) {
  unsigned u = (k & 0x80000000u) ? (k & 0x7fffffffu) : ~k;
  return __uint_as_float(u);
}

// ---------------- adj (fp32 0/1) -> bitmask, one wave-ballot per 64 j ----
__global__ __launch_bounds__(256) void adj2bits(const float* __restrict__ adj,
                                                unsigned long long* __restrict__ bits) {
  const int t = threadIdx.x;
#pragma unroll
  for (int it = 0; it < 4; ++it) {
    size_t gid = (size_t)it * (16384u * 256u) + (size_t)blockIdx.x * 256 + t;
    float v = adj[gid];
    unsigned long long m = __ballot(v != 0.f);
    if ((t & 63) == 0) bits[gid >> 6] = m;
  }
}

// ---------------- fused producer: MFMA GEMM (Markidis split) + epilogue ----
// Block (bi,bo): rows bi*64..+63 x head bo's 64 features. Outputs:
// GT16[h][f][j] (f-major fp16 panels for the dense attention), elT[h][i],
// erT[h][j], ermax (atomicMax monotone keys). XOR-swizzled LDS (validated R6).
__global__ __launch_bounds__(256, 2) void gemm_fused(
    const float* __restrict__ H, const float* __restrict__ Wt,
    const float* __restrict__ a,
    _Float16* __restrict__ GT16, float* __restrict__ elT, float* __restrict__ erT,
    unsigned* __restrict__ ermax_keys) {
  __shared__ _Float16 Ah[64 * KC];  // 16 KB each
  __shared__ _Float16 Al[64 * KC];
  __shared__ _Float16 Bh[64 * KC];
  __shared__ _Float16 Bl[64 * KC];
  const int t = threadIdx.x;
  const int w = t >> 6, l = t & 63;
  const int n16 = l & 15, q = l >> 4;
  const int bi = blockIdx.x, bo = blockIdx.y;
  const int m0 = bi * 64 + w * 16;

  floatx4 acc[4];
#pragma unroll
  for (int ct = 0; ct < 4; ++ct) acc[ct] = (floatx4)0.f;

  for (int kc = 0; kc < 2; ++kc) {
    if (kc) __syncthreads();
#pragma unroll
    for (int p = 0; p < 8; ++p) {
      const int idx = p * 256 + t;
      const int r = idx >> 5;
      const int c4 = (idx & 31) << 2;
      const int dst = r * KC + (((idx & 31) >> 1) ^ (r & 7)) * 8 + (idx & 1) * 4;
      float4 hv = *(const float4*)(H + (size_t)(bi * 64 + r) * IN_FEAT + kc * KC + c4);
      float4 wv = *(const float4*)(Wt + (size_t)(bo * 64 + r) * IN_FEAT + kc * KC + c4);
      union { _Float16 h[4]; int2 d; } hh_, hl_, wh_, wl_;
      hh_.h[0] = (_Float16)hv.x; hh_.h[1] = (_Float16)hv.y;
      hh_.h[2] = (_Float16)hv.z; hh_.h[3] = (_Float16)hv.w;
      hl_.h[0] = (_Float16)(hv.x - (float)hh_.h[0]);
      hl_.h[1] = (_Float16)(hv.y - (float)hh_.h[1]);
      hl_.h[2] = (_Float16)(hv.z - (float)hh_.h[2]);
      hl_.h[3] = (_Float16)(hv.w - (float)hh_.h[3]);
      wh_.h[0] = (_Float16)wv.x; wh_.h[1] = (_Float16)wv.y;
      wh_.h[2] = (_Float16)wv.z; wh_.h[3] = (_Float16)wv.w;
      wl_.h[0] = (_Float16)(wv.x - (float)wh_.h[0]);
      wl_.h[1] = (_Float16)(wv.y - (float)wh_.h[1]);
      wl_.h[2] = (_Float16)(wv.z - (float)wh_.h[2]);
      wl_.h[3] = (_Float16)(wv.w - (float)wh_.h[3]);
      *(int2*)&Ah[dst] = hh_.d;
      *(int2*)&Al[dst] = hl_.d;
      *(int2*)&Bh[dst] = wh_.d;
      *(int2*)&Bl[dst] = wl_.d;
    }
    __syncthreads();
#pragma unroll
    for (int ks = 0; ks < 4; ++ks) {
      const int aoff = (w * 16 + n16) * KC + (((ks << 2) + q) ^ (n16 & 7)) * 8;
      half8 Afh = *(const half8*)&Ah[aoff];
      half8 Afl = *(const half8*)&Al[aoff];
#pragma unroll
      for (int ct = 0; ct < 4; ++ct) {
        const int boff = (ct * 16 + n16) * KC + (((ks << 2) + q) ^ (n16 & 7)) * 8;
        half8 Bfh = *(const half8*)&Bh[boff];
        half8 Bfl = *(const half8*)&Bl[boff];
        acc[ct] = __builtin_amdgcn_mfma_f32_16x16x32_f16(Afh, Bfh, acc[ct], 0, 0, 0);
        acc[ct] = __builtin_amdgcn_mfma_f32_16x16x32_f16(Afl, Bfh, acc[ct], 0, 0, 0);
        acc[ct] = __builtin_amdgcn_mfma_f32_16x16x32_f16(Afh, Bfl, acc[ct], 0, 0, 0);
      }
    }
  }

  // ---- epilogue: el/er (head-major), ermax ----
  float aLv[4], aRv[4];
#pragma unroll
  for (int ct = 0; ct < 4; ++ct) {
    aLv[ct] = a[ct * 16 + n16];
    aRv[ct] = a[64 + ct * 16 + n16];
  }
  float erv[4];
#pragma unroll
  for (int reg = 0; reg < 4; ++reg) {
    float sl = 0.f, sr = 0.f;
#pragma unroll
    for (int ct = 0; ct < 4; ++ct) {
      sl = fmaf(acc[ct][reg], aLv[ct], sl);
      sr = fmaf(acc[ct][reg], aRv[ct], sr);
    }
#pragma unroll
    for (int off = 1; off < 16; off <<= 1) {
      sl += __shfl_xor(sl, off);
      sr += __shfl_xor(sr, off);
    }
    erv[reg] = sr;
    if (n16 == 0) {
      const int rowi = m0 + q * 4 + reg;
      elT[(size_t)bo * N_NODES + rowi] = sl;
      erT[(size_t)bo * N_NODES + rowi] = sr;
    }
  }
  {
    float mx = fmaxf(fmaxf(erv[0], erv[1]), fmaxf(erv[2], erv[3]));
    mx = fmaxf(mx, __shfl_xor(mx, 16));
    mx = fmaxf(mx, __shfl_xor(mx, 32));
    if (l == 0) atomicMax(ermax_keys + bo, fkey(mx));
  }

  // ---- GT16[h][f][j]: LDS bounce + transpose -> coalesced stores ----
  __syncthreads();
  _Float16* LG = Ah;  // 64 x 72 halfs
#pragma unroll
  for (int ct = 0; ct < 4; ++ct)
#pragma unroll
    for (int reg = 0; reg < 4; ++reg)
      LG[(w * 16 + q * 4 + reg) * 72 + ct * 16 + n16] = (_Float16)acc[ct][reg];
  __syncthreads();
  {
    const int f = t >> 2, jq = t & 3;
    union { _Float16 hh[16]; int4 v[2]; } u;
#pragma unroll
    for (int k = 0; k < 16; ++k) u.hh[k] = LG[(jq * 16 + k) * 72 + f];
    _Float16* dst = GT16 + (size_t)(bo * 64 + f) * N_NODES + bi * 64 + jq * 16;
    *(int4*)dst = u.v[0];
    *(int4*)(dst + 8) = u.v[1];
  }
}

// ---------------- dense flash attention v2 ----------------
// Grid (64 i-tiles, 8 heads), 256 threads. Per j-tile of 64:
//   P[i][j] = bit ? exp(lrelu(el+er)-m_i) : exp(-m_i)   (fp16, XOR-swizzled LDS)
//   out[64i x 64f] += P @ GT16-tile (MFMA), Z accumulated in fp32.
// m_i = max(0, el[i,h]+ermax[h]) upper-bounds all exponents (lrelu(x)<=max(x,0)).
__global__ __launch_bounds__(256, 2) void attn_dense2(
    const unsigned long long* __restrict__ bits, const _Float16* __restrict__ GT16,
    const float* __restrict__ elT, const float* __restrict__ erT,
    const unsigned* __restrict__ ermax_keys, float* __restrict__ out) {
  __shared__ _Float16 P[64 * 64];       // 8 KB
  __shared__ _Float16 Gt[2][64 * 64];   // 16 KB
  __shared__ float ers[2][64];
  __shared__ float els[64], ms[64], ems[64], Zs[64];

  const int t = threadIdx.x;
  const int ib = blockIdx.x, h = blockIdx.y;
  const int i0 = ib * 64;
  const int pi = t >> 2, pj = t & 3;            // P-gen role
  const int w = t >> 6, n16 = t & 15, q = (t & 63) >> 4;  // MFMA role

  // prologue: el/m/em per row; stage tile 0
  if (t < 64) {
    float e = elT[(size_t)h * N_NODES + i0 + t];
    float m = fmaxf(0.f, e + fkey_inv(ermax_keys[h]));
    els[t] = e; ms[t] = m; ems[t] = __expf(-m);
    ers[0][t] = erT[(size_t)h * N_NODES + t];
  }
  {
    const int sf = t >> 2, sseg = t & 3;
    const _Float16* src = GT16 + (size_t)(h * 64 + sf) * N_NODES + sseg * 16;
    int4 v0 = *(const int4*)src;
    int4 v1 = *(const int4*)(src + 8);
    *(int4*)&Gt[0][sf * 64 + ((sseg * 2) ^ (sf & 7)) * 8] = v0;
    *(int4*)&Gt[0][sf * 64 + ((sseg * 2 + 1) ^ (sf & 7)) * 8] = v1;
  }
  __syncthreads();

  const float el_i = els[pi], m_i = ms[pi], em_i = ems[pi];
  const unsigned long long* brow = bits + (size_t)(i0 + pi) * 64;
  float zacc = 0.f;

  floatx4 acc[4];
#pragma unroll
  for (int ft = 0; ft < 4; ++ft) acc[ft] = (floatx4)0.f;

  int par = 0;
  for (int s = 0; s < 64; ++s) {
    // ---- P-gen (16 elements per thread) ----
    {
      const unsigned long long bv = brow[s];
      union { _Float16 hh[16]; int4 v[2]; } up;
      float z0 = 0.f;
#pragma unroll
      for (int k = 0; k < 16; ++k) {
        const int jl = pj * 16 + k;
        float x = el_i + ers[par][jl];
        x = fmaxf(x, NEG_SLOPE * x);
        float p = __expf(x - m_i);
        float sel = ((bv >> jl) & 1ull) ? p : em_i;
        z0 += sel;
        up.hh[k] = (_Float16)sel;
      }
      zacc += z0;
      *(int4*)&P[pi * 64 + ((pj * 2) ^ (pi & 7)) * 8] = up.v[0];
      *(int4*)&P[pi * 64 + ((pj * 2 + 1) ^ (pi & 7)) * 8] = up.v[1];
    }
    __syncthreads();
    // ---- stage next tile (other parity) ----
    if (s + 1 < 64) {
      const int sf = t >> 2, sseg = t & 3;
      const _Float16* src = GT16 + (size_t)(h * 64 + sf) * N_NODES + (s + 1) * 64 + sseg * 16;
      int4 v0 = *(const int4*)src;
      int4 v1 = *(const int4*)(src + 8);
      *(int4*)&Gt[par ^ 1][sf * 64 + ((sseg * 2) ^ (sf & 7)) * 8] = v0;
      *(int4*)&Gt[par ^ 1][sf * 64 + ((sseg * 2 + 1) ^ (sf & 7)) * 8] = v1;
      if (t < 64) ers[par ^ 1][t] = erT[(size_t)h * N_NODES + (s + 1) * 64 + t];
    }
    // ---- MFMA: out[64i,64f] += P @ Gt ----
#pragma unroll
    for (int ks = 0; ks < 2; ++ks) {
      half8 Af = *(const half8*)&P[(w * 16 + n16) * 64 + (((ks << 2) + q) ^ (n16 & 7)) * 8];
#pragma unroll
      for (int ft = 0; ft < 4; ++ft) {
        half8 Bf = *(const half8*)&Gt[par][(ft * 16 + n16) * 64 + (((ks << 2) + q) ^ (n16 & 7)) * 8];
        acc[ft] = __builtin_amdgcn_mfma_f32_16x16x32_f16(Af, Bf, acc[ft], 0, 0, 0);
      }
    }
    __syncthreads();
    par ^= 1;
  }

  // ---- Z: threads 4*pi..4*pi+3 hold row pi's partials ----
  {
    float z = zacc;
    z += __shfl_xor(z, 1);
    z += __shfl_xor(z, 2);
    if (pj == 0) Zs[pi] = z;
  }
  __syncthreads();

  // ---- normalize & store: C/D row=q*4+reg (i), col=n16 (f) ----
#pragma unroll
  for (int reg = 0; reg < 4; ++reg) {
    const int il = w * 16 + q * 4 + reg;
    const float iz = 1.f / Zs[il];
    float* op = out + (size_t)(i0 + il) * OUT_FEAT + h * 64;
#pragma unroll
    for (int ft = 0; ft < 4; ++ft) op[ft * 16 + n16] = acc[ft][reg] * iz;
  }
}

extern "C" void kernel_launch(void* const* d_in, const int* in_sizes, int n_in,
                              void* d_out, int out_size, void* d_ws, size_t ws_size,
                              hipStream_t stream) {
  const float* h   = (const float*)d_in[0];
  const float* adj = (const float*)d_in[1];
  const float* W   = (const float*)d_in[2];
  const float* a   = (const float*)d_in[3];
  float* out = (float*)d_out;

  char* ws = (char*)d_ws;
  _Float16* GT16 = (_Float16*)ws;                                   // 4 MB
  unsigned long long* bits = (unsigned long long*)(ws + 4u * 1024 * 1024);  // 2 MB
  float* elT = (float*)(ws + 6u * 1024 * 1024);                     // 128 KB
  float* erT = (float*)(ws + 6u * 1024 * 1024 + 128 * 1024);        // 128 KB
  unsigned* ermax_keys = (unsigned*)(ws + 6u * 1024 * 1024 + 256 * 1024);  // 32 B

  hipMemsetAsync(ermax_keys, 0, 32, stream);  // key 0 decodes below any real er
  adj2bits<<<dim3(16384), 256, 0, stream>>>(adj, bits);
  gemm_fused<<<dim3(64, 8), 256, 0, stream>>>(h, W, a, GT16, elT, erT, ermax_keys);
  attn_dense2<<<dim3(64, 8), 256, 0, stream>>>(bits, GT16, elT, erT, ermax_keys, out);
}

// Round 8
// 176.696 us; speedup vs baseline: 1.3232x; 1.3232x over previous
//
#include <hip/hip_runtime.h>

#define N_NODES 4096
#define IN_FEAT 256
#define N_HEADS 8
#define N_HIDDEN 64
#define OUT_FEAT (N_HEADS * N_HIDDEN)  // 512
#define NEG_SLOPE 0.2f

typedef _Float16 half8 __attribute__((ext_vector_type(8)));
typedef float floatx4 __attribute__((ext_vector_type(4)));

// ---------------- zero d_out (2M floats) + Zp (32K floats) ----------------
__global__ __launch_bounds__(256) void zero_kern(float* __restrict__ out,
                                                 float* __restrict__ Zp) {
  const int g = blockIdx.x * 256 + threadIdx.x;
  *(float4*)(out + (size_t)g * 4) = make_float4(0.f, 0.f, 0.f, 0.f);
  if (blockIdx.x < 32) *(float4*)(Zp + (size_t)g * 4) = make_float4(0.f, 0.f, 0.f, 0.f);
}

// ---------------- fat producer: MFMA GEMM + epilogue | adj->bits ----------
// blockIdx.y < 8: GEMM block (bi=x, bo=y): G-tile rows x*64..+63, head y.
//   Markidis fp16 hi/lo split, XOR-swizzled LDS (R6/R7-validated, 0 conflicts).
//   Epilogue: GT16[h][f][j] (transposed fp16), elT[h][i], eR1/eR2[h][j]
//   (= exp(er), exp(0.2*er); no max-shift needed: el+er <= ~7 so P <= e^7
//   fits fp16 with full relative precision; softmax is shift-invariant).
// blockIdx.y >= 8: adj-bits block: rows [c*8, c*8+8), c = x*8+(y-8).
__global__ __launch_bounds__(256) void produce(
    const float* __restrict__ H, const float* __restrict__ adj,
    const float* __restrict__ Wt, const float* __restrict__ a,
    _Float16* __restrict__ GT16, float* __restrict__ elT,
    float* __restrict__ eR1, float* __restrict__ eR2,
    unsigned long long* __restrict__ bits) {
  __shared__ _Float16 SM[4 * 64 * 64];  // 32 KB: Ah|Al|Bh|Bl
  const int t = threadIdx.x;
  const int bx = blockIdx.x, by = blockIdx.y;

  if (by >= 8) {
    // ---- adj (fp32 0/1) -> 64-bit masks; 8 loads in flight per ballot run
    const int c = bx * 8 + (by - 8);
    const size_t W0 = (size_t)c * 512;
    const int wv = t >> 6, lane = t & 63;
    for (int k0 = 0; k0 < 128; k0 += 8) {
      float v[8];
#pragma unroll
      for (int k = 0; k < 8; ++k)
        v[k] = adj[(W0 + wv * 128 + k0 + k) * 64 + lane];
#pragma unroll
      for (int k = 0; k < 8; ++k) {
        unsigned long long m = __ballot(v[k] != 0.f);
        if (lane == 0) bits[W0 + wv * 128 + k0 + k] = m;
      }
    }
    return;
  }

  _Float16* Ah = SM;
  _Float16* Al = SM + 4096;
  _Float16* Bh = SM + 8192;
  _Float16* Bl = SM + 12288;
  const int w = t >> 6, l = t & 63;
  const int n16 = l & 15, q = l >> 4;
  const int bi = bx, bo = by;
  const int m0 = bi * 64 + w * 16;

  floatx4 acc[4];
#pragma unroll
  for (int ct = 0; ct < 4; ++ct) acc[ct] = (floatx4)0.f;

  for (int kc = 0; kc < 4; ++kc) {
    if (kc) __syncthreads();
#pragma unroll
    for (int p = 0; p < 4; ++p) {
      const int idx = p * 256 + t;
      const int r = idx >> 4;
      const int c4 = (idx & 15) << 2;
      const int dst = r * 64 + ((((idx & 15) >> 1)) ^ (r & 7)) * 8 + (idx & 1) * 4;
      float4 hv = *(const float4*)(H + (size_t)(bi * 64 + r) * IN_FEAT + kc * 64 + c4);
      float4 wv = *(const float4*)(Wt + (size_t)(bo * 64 + r) * IN_FEAT + kc * 64 + c4);
      union { _Float16 h[4]; int2 d; } hh_, hl_, wh_, wl_;
      hh_.h[0] = (_Float16)hv.x; hh_.h[1] = (_Float16)hv.y;
      hh_.h[2] = (_Float16)hv.z; hh_.h[3] = (_Float16)hv.w;
      hl_.h[0] = (_Float16)(hv.x - (float)hh_.h[0]);
      hl_.h[1] = (_Float16)(hv.y - (float)hh_.h[1]);
      hl_.h[2] = (_Float16)(hv.z - (float)hh_.h[2]);
      hl_.h[3] = (_Float16)(hv.w - (float)hh_.h[3]);
      wh_.h[0] = (_Float16)wv.x; wh_.h[1] = (_Float16)wv.y;
      wh_.h[2] = (_Float16)wv.z; wh_.h[3] = (_Float16)wv.w;
      wl_.h[0] = (_Float16)(wv.x - (float)wh_.h[0]);
      wl_.h[1] = (_Float16)(wv.y - (float)wh_.h[1]);
      wl_.h[2] = (_Float16)(wv.z - (float)wh_.h[2]);
      wl_.h[3] = (_Float16)(wv.w - (float)wh_.h[3]);
      *(int2*)&Ah[dst] = hh_.d;
      *(int2*)&Al[dst] = hl_.d;
      *(int2*)&Bh[dst] = wh_.d;
      *(int2*)&Bl[dst] = wl_.d;
    }
    __syncthreads();
#pragma unroll
    for (int ks = 0; ks < 2; ++ks) {
      const int ao = (w * 16 + n16) * 64 + (((ks << 2) + q) ^ (n16 & 7)) * 8;
      half8 Afh = *(const half8*)&Ah[ao];
      half8 Afl = *(const half8*)&Al[ao];
#pragma unroll
      for (int ct = 0; ct < 4; ++ct) {
        const int bofs = (ct * 16 + n16) * 64 + (((ks << 2) + q) ^ (n16 & 7)) * 8;
        half8 Bfh = *(const half8*)&Bh[bofs];
        half8 Bfl = *(const half8*)&Bl[bofs];
        acc[ct] = __builtin_amdgcn_mfma_f32_16x16x32_f16(Afh, Bfh, acc[ct], 0, 0, 0);
        acc[ct] = __builtin_amdgcn_mfma_f32_16x16x32_f16(Afl, Bfh, acc[ct], 0, 0, 0);
        acc[ct] = __builtin_amdgcn_mfma_f32_16x16x32_f16(Afh, Bfl, acc[ct], 0, 0, 0);
      }
    }
  }

  // ---- epilogue: el/er dots -> elT, eR1=exp(er), eR2=exp(0.2 er) ----
  float aLv[4], aRv[4];
#pragma unroll
  for (int ct = 0; ct < 4; ++ct) {
    aLv[ct] = a[ct * 16 + n16];
    aRv[ct] = a[64 + ct * 16 + n16];
  }
#pragma unroll
  for (int reg = 0; reg < 4; ++reg) {
    float sl = 0.f, sr = 0.f;
#pragma unroll
    for (int ct = 0; ct < 4; ++ct) {
      sl = fmaf(acc[ct][reg], aLv[ct], sl);
      sr = fmaf(acc[ct][reg], aRv[ct], sr);
    }
#pragma unroll
    for (int off = 1; off < 16; off <<= 1) {
      sl += __shfl_xor(sl, off);
      sr += __shfl_xor(sr, off);
    }
    if (n16 == 0) {
      const int rowi = m0 + q * 4 + reg;
      elT[(size_t)bo * N_NODES + rowi] = sl;
      eR1[(size_t)bo * N_NODES + rowi] = __expf(sr);
      eR2[(size_t)bo * N_NODES + rowi] = __expf(0.2f * sr);
    }
  }

  // ---- GT16[h][f][j]: LDS bounce + transpose -> coalesced stores ----
  __syncthreads();
  _Float16* LG = SM;  // 64 x 72 halfs (9216 B)
#pragma unroll
  for (int ct = 0; ct < 4; ++ct)
#pragma unroll
    for (int reg = 0; reg < 4; ++reg)
      LG[(w * 16 + q * 4 + reg) * 72 + ct * 16 + n16] = (_Float16)acc[ct][reg];
  __syncthreads();
  {
    const int f = t >> 2, jq = t & 3;
    union { _Float16 hh[16]; int4 v[2]; } u;
#pragma unroll
    for (int k = 0; k < 16; ++k) u.hh[k] = LG[(jq * 16 + k) * 72 + f];
    _Float16* dst = GT16 + (size_t)(bo * 64 + f) * N_NODES + bi * 64 + jq * 16;
    *(int4*)dst = u.v[0];
    *(int4*)(dst + 8) = u.v[1];
  }
}

// ---------------- dense attention v3: exp-free P in A-frag registers ------
// Grid (64 i-tiles, 8 heads, 4 j-splits). Per 64-j step:
//   p = bit ? (el+er>0 ? e^el*e^er : e^{.2el}*e^{.2er}) : 1   (exact lrelu split;
//   branch test el+er>0 <=> eR1_j > e^{-el_i})
// Lane (q,n16) of wave w computes exactly its MFMA A-operand values
// A[m=n16][k=q*8+j] -> no P LDS round-trip, one barrier per step.
// Partial out/Z accumulated with device-scope fp32 atomics into d_out/Zp.
__global__ __launch_bounds__(256) void attn_v3(
    const unsigned long long* __restrict__ bits, const _Float16* __restrict__ GT16,
    const float* __restrict__ elT, const float* __restrict__ eR1,
    const float* __restrict__ eR2, float* __restrict__ out, float* __restrict__ Zp) {
  __shared__ _Float16 Gt[2][64 * 64];           // 16 KB
  __shared__ float eRs1[2][64], eRs2[2][64];    // 1 KB
  __shared__ unsigned long long bitsS[2][64];   // 1 KB
  __shared__ float eL1s[64], eL2s[64], ethrs[64];

  const int t = threadIdx.x;
  const int ib = blockIdx.x, h = blockIdx.y, s = blockIdx.z;
  const int i0 = ib * 64;
  const int jb0 = s * 1024;
  const int w = t >> 6, l = t & 63, n16 = l & 15, q = l >> 4;

  auto stage = [&](int par, int step) {
    if (t < 64) {
      eRs1[par][t] = eR1[(size_t)h * N_NODES + jb0 + step * 64 + t];
    } else if (t < 128) {
      eRs2[par][t - 64] = eR2[(size_t)h * N_NODES + jb0 + step * 64 + (t - 64)];
    } else if (t < 192) {
      bitsS[par][t - 128] = bits[(size_t)(i0 + t - 128) * 64 + s * 16 + step];
    }
    const int sf = t >> 2, sseg = t & 3;
    const _Float16* src = GT16 + (size_t)(h * 64 + sf) * N_NODES + jb0 + step * 64 + sseg * 16;
    int4 v0 = *(const int4*)src;
    int4 v1 = *(const int4*)(src + 8);
    *(int4*)&Gt[par][sf * 64 + ((sseg * 2) ^ (sf & 7)) * 8] = v0;
    *(int4*)&Gt[par][sf * 64 + ((sseg * 2 + 1) ^ (sf & 7)) * 8] = v1;
  };

  if (t < 64) {
    float e = elT[(size_t)h * N_NODES + i0 + t];
    eL1s[t] = __expf(e);
    eL2s[t] = __expf(0.2f * e);
    ethrs[t] = __expf(-e);
  }
  stage(0, 0);
  __syncthreads();

  const float eL1 = eL1s[w * 16 + n16];
  const float eL2 = eL2s[w * 16 + n16];
  const float ethr = ethrs[w * 16 + n16];

  floatx4 acc[4];
#pragma unroll
  for (int ft = 0; ft < 4; ++ft) acc[ft] = (floatx4)0.f;
  float zacc = 0.f;

  int par = 0;
  for (int step = 0; step < 16; ++step) {
    if (step + 1 < 16) stage(par ^ 1, step + 1);
    const unsigned long long bv = bitsS[par][w * 16 + n16];
#pragma unroll
    for (int ks = 0; ks < 2; ++ks) {
      const int j8 = ks * 32 + q * 8;
      const unsigned byte = (unsigned)(bv >> j8) & 0xffu;
      float4 r1a = *(const float4*)&eRs1[par][j8];
      float4 r1b = *(const float4*)&eRs1[par][j8 + 4];
      float4 r2a = *(const float4*)&eRs2[par][j8];
      float4 r2b = *(const float4*)&eRs2[par][j8 + 4];
      float r1[8] = {r1a.x, r1a.y, r1a.z, r1a.w, r1b.x, r1b.y, r1b.z, r1b.w};
      float r2[8] = {r2a.x, r2a.y, r2a.z, r2a.w, r2b.x, r2b.y, r2b.z, r2b.w};
      half8 Af;
#pragma unroll
      for (int k = 0; k < 8; ++k) {
        const bool pos = r1[k] > ethr;
        const float pv = (pos ? eL1 : eL2) * (pos ? r1[k] : r2[k]);
        const float p = ((byte >> k) & 1u) ? pv : 1.0f;
        zacc += p;
        Af[k] = (_Float16)p;
      }
#pragma unroll
      for (int ft = 0; ft < 4; ++ft) {
        half8 Bf = *(const half8*)&Gt[par][(ft * 16 + n16) * 64 + ((ks * 4 + q) ^ (n16 & 7)) * 8];
        acc[ft] = __builtin_amdgcn_mfma_f32_16x16x32_f16(Af, Bf, acc[ft], 0, 0, 0);
      }
    }
    __syncthreads();
    par ^= 1;
  }

  // ---- Z: reduce over q-duplicates, one atomic per row per wave ----
  zacc += __shfl_xor(zacc, 16);
  zacc += __shfl_xor(zacc, 32);
  if (q == 0) atomicAdd(Zp + (size_t)h * N_NODES + i0 + w * 16 + n16, zacc);

  // ---- out partial: C/D row=q*4+reg (i), col=n16 (f); coalesced atomics ----
#pragma unroll
  for (int ft = 0; ft < 4; ++ft)
#pragma unroll
    for (int reg = 0; reg < 4; ++reg)
      atomicAdd(out + (size_t)(i0 + w * 16 + q * 4 + reg) * OUT_FEAT + h * 64 + ft * 16 + n16,
                acc[ft][reg]);
}

// ---------------- normalize: out[i,h,f] /= Z[h,i] ----------------
__global__ __launch_bounds__(256) void normalize(float* __restrict__ out,
                                                 const float* __restrict__ Zp) {
  const int o = (blockIdx.x * 256 + threadIdx.x) * 4;
  const int i = o >> 9, h = (o >> 6) & 7;
  const float iz = 1.f / Zp[(size_t)h * N_NODES + i];
  float4 v = *(float4*)(out + o);
  v.x *= iz; v.y *= iz; v.z *= iz; v.w *= iz;
  *(float4*)(out + o) = v;
}

extern "C" void kernel_launch(void* const* d_in, const int* in_sizes, int n_in,
                              void* d_out, int out_size, void* d_ws, size_t ws_size,
                              hipStream_t stream) {
  const float* h   = (const float*)d_in[0];
  const float* adj = (const float*)d_in[1];
  const float* W   = (const float*)d_in[2];
  const float* a   = (const float*)d_in[3];
  float* out = (float*)d_out;

  char* ws = (char*)d_ws;
  _Float16* GT16 = (_Float16*)ws;                                         // 4 MB
  unsigned long long* bits = (unsigned long long*)(ws + 4u * 1024 * 1024);// 2 MB
  float* elT = (float*)(ws + 6u * 1024 * 1024);                           // 128 KB
  float* eR1 = (float*)(ws + 6u * 1024 * 1024 + 128 * 1024);              // 128 KB
  float* eR2 = (float*)(ws + 6u * 1024 * 1024 + 256 * 1024);              // 128 KB
  float* Zp  = (float*)(ws + 6u * 1024 * 1024 + 384 * 1024);              // 128 KB

  zero_kern<<<dim3(2048), 256, 0, stream>>>(out, Zp);
  produce<<<dim3(64, 16), 256, 0, stream>>>(h, adj, W, a, GT16, elT, eR1, eR2, bits);
  attn_v3<<<dim3(64, 8, 4), 256, 0, stream>>>(bits, GT16, elT, eR1, eR2, out, Zp);
  normalize<<<dim3(2048), 256, 0, stream>>>(out, Zp);
}

// Round 9
// 169.211 us; speedup vs baseline: 1.3817x; 1.0442x over previous
//
#include <hip/hip_runtime.h>

#define N_NODES 4096
#define IN_FEAT 256
#define N_HEADS 8
#define N_HIDDEN 64
#define OUT_FEAT (N_HEADS * N_HIDDEN)  // 512
#define NEG_SLOPE 0.2f

typedef _Float16 half8 __attribute__((ext_vector_type(8)));
typedef float floatx4 __attribute__((ext_vector_type(4)));

// ---------------- fat producer: MFMA GEMM + epilogue | adj->bits ----------
// (validated R8 kernel, unchanged except dropped outputs)
// blockIdx.y < 8: GEMM block (bi=x, bo=y). Markidis fp16 hi/lo split,
//   XOR-swizzled LDS (0 bank conflicts measured). Epilogue: GT16[h][f][j],
//   elT[h][i], eR1=exp(er), eR2=exp(0.2*er). No max-shift needed:
//   el+er <= ~9 -> P <= e^9 fits fp16; softmax is shift-invariant.
// blockIdx.y >= 8: adj-bits block: rows [c*8, c*8+8), c = x*8+(y-8).
__global__ __launch_bounds__(256) void produce(
    const float* __restrict__ H, const float* __restrict__ adj,
    const float* __restrict__ Wt, const float* __restrict__ a,
    _Float16* __restrict__ GT16, float* __restrict__ elT,
    float* __restrict__ eR1, float* __restrict__ eR2,
    unsigned long long* __restrict__ bits) {
  __shared__ _Float16 SM[4 * 64 * 64];  // 32 KB: Ah|Al|Bh|Bl
  const int t = threadIdx.x;
  const int bx = blockIdx.x, by = blockIdx.y;

  if (by >= 8) {
    const int c = bx * 8 + (by - 8);
    const size_t W0 = (size_t)c * 512;
    const int wv = t >> 6, lane = t & 63;
    for (int k0 = 0; k0 < 128; k0 += 8) {
      float v[8];
#pragma unroll
      for (int k = 0; k < 8; ++k)
        v[k] = adj[(W0 + wv * 128 + k0 + k) * 64 + lane];
#pragma unroll
      for (int k = 0; k < 8; ++k) {
        unsigned long long m = __ballot(v[k] != 0.f);
        if (lane == 0) bits[W0 + wv * 128 + k0 + k] = m;
      }
    }
    return;
  }

  _Float16* Ah = SM;
  _Float16* Al = SM + 4096;
  _Float16* Bh = SM + 8192;
  _Float16* Bl = SM + 12288;
  const int w = t >> 6, l = t & 63;
  const int n16 = l & 15, q = l >> 4;
  const int bi = bx, bo = by;
  const int m0 = bi * 64 + w * 16;

  floatx4 acc[4];
#pragma unroll
  for (int ct = 0; ct < 4; ++ct) acc[ct] = (floatx4)0.f;

  for (int kc = 0; kc < 4; ++kc) {
    if (kc) __syncthreads();
#pragma unroll
    for (int p = 0; p < 4; ++p) {
      const int idx = p * 256 + t;
      const int r = idx >> 4;
      const int c4 = (idx & 15) << 2;
      const int dst = r * 64 + ((((idx & 15) >> 1)) ^ (r & 7)) * 8 + (idx & 1) * 4;
      float4 hv = *(const float4*)(H + (size_t)(bi * 64 + r) * IN_FEAT + kc * 64 + c4);
      float4 wv = *(const float4*)(Wt + (size_t)(bo * 64 + r) * IN_FEAT + kc * 64 + c4);
      union { _Float16 h[4]; int2 d; } hh_, hl_, wh_, wl_;
      hh_.h[0] = (_Float16)hv.x; hh_.h[1] = (_Float16)hv.y;
      hh_.h[2] = (_Float16)hv.z; hh_.h[3] = (_Float16)hv.w;
      hl_.h[0] = (_Float16)(hv.x - (float)hh_.h[0]);
      hl_.h[1] = (_Float16)(hv.y - (float)hh_.h[1]);
      hl_.h[2] = (_Float16)(hv.z - (float)hh_.h[2]);
      hl_.h[3] = (_Float16)(hv.w - (float)hh_.h[3]);
      wh_.h[0] = (_Float16)wv.x; wh_.h[1] = (_Float16)wv.y;
      wh_.h[2] = (_Float16)wv.z; wh_.h[3] = (_Float16)wv.w;
      wl_.h[0] = (_Float16)(wv.x - (float)wh_.h[0]);
      wl_.h[1] = (_Float16)(wv.y - (float)wh_.h[1]);
      wl_.h[2] = (_Float16)(wv.z - (float)wh_.h[2]);
      wl_.h[3] = (_Float16)(wv.w - (float)wh_.h[3]);
      *(int2*)&Ah[dst] = hh_.d;
      *(int2*)&Al[dst] = hl_.d;
      *(int2*)&Bh[dst] = wh_.d;
      *(int2*)&Bl[dst] = wl_.d;
    }
    __syncthreads();
#pragma unroll
    for (int ks = 0; ks < 2; ++ks) {
      const int ao = (w * 16 + n16) * 64 + (((ks << 2) + q) ^ (n16 & 7)) * 8;
      half8 Afh = *(const half8*)&Ah[ao];
      half8 Afl = *(const half8*)&Al[ao];
#pragma unroll
      for (int ct = 0; ct < 4; ++ct) {
        const int bofs = (ct * 16 + n16) * 64 + (((ks << 2) + q) ^ (n16 & 7)) * 8;
        half8 Bfh = *(const half8*)&Bh[bofs];
        half8 Bfl = *(const half8*)&Bl[bofs];
        acc[ct] = __builtin_amdgcn_mfma_f32_16x16x32_f16(Afh, Bfh, acc[ct], 0, 0, 0);
        acc[ct] = __builtin_amdgcn_mfma_f32_16x16x32_f16(Afl, Bfh, acc[ct], 0, 0, 0);
        acc[ct] = __builtin_amdgcn_mfma_f32_16x16x32_f16(Afh, Bfl, acc[ct], 0, 0, 0);
      }
    }
  }

  float aLv[4], aRv[4];
#pragma unroll
  for (int ct = 0; ct < 4; ++ct) {
    aLv[ct] = a[ct * 16 + n16];
    aRv[ct] = a[64 + ct * 16 + n16];
  }
#pragma unroll
  for (int reg = 0; reg < 4; ++reg) {
    float sl = 0.f, sr = 0.f;
#pragma unroll
    for (int ct = 0; ct < 4; ++ct) {
      sl = fmaf(acc[ct][reg], aLv[ct], sl);
      sr = fmaf(acc[ct][reg], aRv[ct], sr);
    }
#pragma unroll
    for (int off = 1; off < 16; off <<= 1) {
      sl += __shfl_xor(sl, off);
      sr += __shfl_xor(sr, off);
    }
    if (n16 == 0) {
      const int rowi = m0 + q * 4 + reg;
      elT[(size_t)bo * N_NODES + rowi] = sl;
      eR1[(size_t)bo * N_NODES + rowi] = __expf(sr);
      eR2[(size_t)bo * N_NODES + rowi] = __expf(0.2f * sr);
    }
  }

  __syncthreads();
  _Float16* LG = SM;  // 64 x 72 halfs
#pragma unroll
  for (int ct = 0; ct < 4; ++ct)
#pragma unroll
    for (int reg = 0; reg < 4; ++reg)
      LG[(w * 16 + q * 4 + reg) * 72 + ct * 16 + n16] = (_Float16)acc[ct][reg];
  __syncthreads();
  {
    const int f = t >> 2, jq = t & 3;
    union { _Float16 hh[16]; int4 v[2]; } u;
#pragma unroll
    for (int k = 0; k < 16; ++k) u.hh[k] = LG[(jq * 16 + k) * 72 + f];
    _Float16* dst = GT16 + (size_t)(bo * 64 + f) * N_NODES + bi * 64 + jq * 16;
    *(int4*)dst = u.v[0];
    *(int4*)(dst + 8) = u.v[1];
  }
}

// ---------------- dense attention v5: 512 threads, internal j-split ------
// Grid (64 i-tiles, 8 heads), 512 threads = 8 waves. Wave w: j-half jh=w>>2
// (j in [jh*2048, jh*2048+2048)), row-tile rt=w&3 (rows i0+rt*16..+15).
// P = bit ? max(eL1*eR1, eL2*eR2) : 1   [exp(lrelu(x)) = max(e^x, e^0.2x)]
// generated straight into MFMA A-fragments. Z via ones-column MFMA (fp32).
// j-half partials combined in LDS; normalized in-block; plain stores.
__global__ __launch_bounds__(512) void attn_v5(
    const unsigned long long* __restrict__ bits, const _Float16* __restrict__ GT16,
    const float* __restrict__ elT, const float* __restrict__ eR1,
    const float* __restrict__ eR2, float* __restrict__ out) {
  __shared__ __align__(16) unsigned char GtRaw[2][2][8192];  // 32 KB [jh][par]
  __shared__ float eRs1[2][2][64], eRs2[2][2][64];           // 2 KB
  __shared__ unsigned long long bitsS[2][2][64];             // 2 KB
  __shared__ float eL1s[64], eL2s[64];                       // 512 B
  __shared__ float ZBuf[2][64];                              // 512 B

  const int t = threadIdx.x;
  const int ib = blockIdx.x, h = blockIdx.y;
  const int i0 = ib * 64;
  const int w = t >> 6, l = t & 63, n16 = l & 15, q = l >> 4;
  const int jh = w >> 2, rt = w & 3;

  auto stage = [&](int par, int step) {
    // Gt: two 64f x 64j fp16 tiles, XOR-swizzled (8-half chunks)
    const int sf = t >> 3, sseg = t & 7;
#pragma unroll
    for (int g = 0; g < 2; ++g) {
      const _Float16* src =
          GT16 + (size_t)(h * 64 + sf) * N_NODES + g * 2048 + step * 64 + sseg * 8;
      int4 v = *(const int4*)src;
      *(int4*)&((_Float16*)GtRaw[g][par])[sf * 64 + (sseg ^ (sf & 7)) * 8] = v;
    }
    if (t < 128) {
      eRs1[t >> 6][par][t & 63] =
          eR1[(size_t)h * N_NODES + (t >> 6) * 2048 + step * 64 + (t & 63)];
    } else if (t < 256) {
      const int u = t - 128;
      eRs2[u >> 6][par][u & 63] =
          eR2[(size_t)h * N_NODES + (u >> 6) * 2048 + step * 64 + (u & 63)];
    } else if (t < 384) {
      const int u = t - 256;
      bitsS[u >> 6][par][u & 63] =
          bits[(size_t)(i0 + (u & 63)) * 64 + (u >> 6) * 32 + step];
    }
  };

  if (t < 64) {
    float e = elT[(size_t)h * N_NODES + i0 + t];
    eL1s[t] = __expf(e);
    eL2s[t] = __expf(0.2f * e);
  }
  stage(0, 0);
  __syncthreads();

  const float eL1 = eL1s[rt * 16 + n16];
  const float eL2 = eL2s[rt * 16 + n16];
  half8 Bones;
#pragma unroll
  for (int k = 0; k < 8; ++k) Bones[k] = (n16 == 0) ? (_Float16)1.f : (_Float16)0.f;

  floatx4 acc[4];
#pragma unroll
  for (int ft = 0; ft < 4; ++ft) acc[ft] = (floatx4)0.f;
  floatx4 acc5 = (floatx4)0.f;

  int par = 0;
  for (int step = 0; step < 32; ++step) {
    if (step + 1 < 32) stage(par ^ 1, step + 1);
    const unsigned long long bv = bitsS[jh][par][rt * 16 + n16];
    const _Float16* gt = (const _Float16*)GtRaw[jh][par];
#pragma unroll
    for (int ks = 0; ks < 2; ++ks) {
      const int j8 = ks * 32 + q * 8;
      const unsigned byte = (unsigned)(bv >> j8) & 0xffu;
      float4 r1a = *(const float4*)&eRs1[jh][par][j8];
      float4 r1b = *(const float4*)&eRs1[jh][par][j8 + 4];
      float4 r2a = *(const float4*)&eRs2[jh][par][j8];
      float4 r2b = *(const float4*)&eRs2[jh][par][j8 + 4];
      float r1[8] = {r1a.x, r1a.y, r1a.z, r1a.w, r1b.x, r1b.y, r1b.z, r1b.w};
      float r2[8] = {r2a.x, r2a.y, r2a.z, r2a.w, r2b.x, r2b.y, r2b.z, r2b.w};
      half8 Af;
#pragma unroll
      for (int k = 0; k < 8; ++k) {
        const float pv = fmaxf(eL1 * r1[k], eL2 * r2[k]);
        const float p = ((byte >> k) & 1u) ? pv : 1.0f;
        Af[k] = (_Float16)p;
      }
#pragma unroll
      for (int ft = 0; ft < 4; ++ft) {
        half8 Bf = *(const half8*)&gt[(ft * 16 + n16) * 64 + (((ks << 2) + q) ^ (n16 & 7)) * 8];
        acc[ft] = __builtin_amdgcn_mfma_f32_16x16x32_f16(Af, Bf, acc[ft], 0, 0, 0);
      }
      acc5 = __builtin_amdgcn_mfma_f32_16x16x32_f16(Af, Bones, acc5, 0, 0, 0);
    }
    __syncthreads();
    par ^= 1;
  }

  // ---- combine j-halves in LDS, normalize, store ----
  float* comb1 = (float*)GtRaw;  // [64][68] fp32 = 17.4 KB (Gt no longer needed)
  if (jh == 1) {
#pragma unroll
    for (int ft = 0; ft < 4; ++ft)
#pragma unroll
      for (int reg = 0; reg < 4; ++reg)
        comb1[(rt * 16 + q * 4 + reg) * 68 + ft * 16 + n16] = acc[ft][reg];
    if (n16 == 0) {
#pragma unroll
      for (int reg = 0; reg < 4; ++reg) ZBuf[0][rt * 16 + q * 4 + reg] = acc5[reg];
    }
  }
  __syncthreads();
  if (jh == 0) {
#pragma unroll
    for (int ft = 0; ft < 4; ++ft)
#pragma unroll
      for (int reg = 0; reg < 4; ++reg)
        acc[ft][reg] += comb1[(rt * 16 + q * 4 + reg) * 68 + ft * 16 + n16];
    if (n16 == 0) {
#pragma unroll
      for (int reg = 0; reg < 4; ++reg)
        ZBuf[1][rt * 16 + q * 4 + reg] = acc5[reg] + ZBuf[0][rt * 16 + q * 4 + reg];
    }
  }
  __syncthreads();
  if (jh == 0) {
#pragma unroll
    for (int reg = 0; reg < 4; ++reg) {
      const int row = rt * 16 + q * 4 + reg;
      const float invz = 1.f / ZBuf[1][row];
      float* op = out + (size_t)(i0 + row) * OUT_FEAT + h * 64;
#pragma unroll
      for (int ft = 0; ft < 4; ++ft) op[ft * 16 + n16] = acc[ft][reg] * invz;
    }
  }
}

extern "C" void kernel_launch(void* const* d_in, const int* in_sizes, int n_in,
                              void* d_out, int out_size, void* d_ws, size_t ws_size,
                              hipStream_t stream) {
  const float* h   = (const float*)d_in[0];
  const float* adj = (const float*)d_in[1];
  const float* W   = (const float*)d_in[2];
  const float* a   = (const float*)d_in[3];
  float* out = (float*)d_out;

  char* ws = (char*)d_ws;
  _Float16* GT16 = (_Float16*)ws;                                         // 4 MB
  unsigned long long* bits = (unsigned long long*)(ws + 4u * 1024 * 1024);// 2 MB
  float* elT = (float*)(ws + 6u * 1024 * 1024);                           // 128 KB
  float* eR1 = (float*)(ws + 6u * 1024 * 1024 + 128 * 1024);              // 128 KB
  float* eR2 = (float*)(ws + 6u * 1024 * 1024 + 256 * 1024);              // 128 KB

  produce<<<dim3(64, 16), 256, 0, stream>>>(h, adj, W, a, GT16, elT, eR1, eR2, bits);
  attn_v5<<<dim3(64, 8), 512, 0, stream>>>(bits, GT16, elT, eR1, eR2, out);
}

// Round 10
// 160.559 us; speedup vs baseline: 1.4562x; 1.0539x over previous
//
#include <hip/hip_runtime.h>

#define N_NODES 4096
#define IN_FEAT 256
#define N_HEADS 8
#define N_HIDDEN 64
#define OUT_FEAT (N_HEADS * N_HIDDEN)  // 512
#define NEG_SLOPE 0.2f

typedef _Float16 half8 __attribute__((ext_vector_type(8)));
typedef _Float16 h2 __attribute__((ext_vector_type(2)));
typedef float floatx4 __attribute__((ext_vector_type(4)));

// ---------------- fat producer: MFMA GEMM + epilogue | adj->bits ----------
// (validated R8/R9 kernel; only change: eR1/eR2 now stored as fp16)
__global__ __launch_bounds__(256) void produce(
    const float* __restrict__ H, const float* __restrict__ adj,
    const float* __restrict__ Wt, const float* __restrict__ a,
    _Float16* __restrict__ GT16, float* __restrict__ elT,
    _Float16* __restrict__ eR1h, _Float16* __restrict__ eR2h,
    unsigned long long* __restrict__ bits) {
  __shared__ _Float16 SM[4 * 64 * 64];  // 32 KB: Ah|Al|Bh|Bl
  const int t = threadIdx.x;
  const int bx = blockIdx.x, by = blockIdx.y;

  if (by >= 8) {
    const int c = bx * 8 + (by - 8);
    const size_t W0 = (size_t)c * 512;
    const int wv = t >> 6, lane = t & 63;
    for (int k0 = 0; k0 < 128; k0 += 8) {
      float v[8];
#pragma unroll
      for (int k = 0; k < 8; ++k)
        v[k] = adj[(W0 + wv * 128 + k0 + k) * 64 + lane];
#pragma unroll
      for (int k = 0; k < 8; ++k) {
        unsigned long long m = __ballot(v[k] != 0.f);
        if (lane == 0) bits[W0 + wv * 128 + k0 + k] = m;
      }
    }
    return;
  }

  _Float16* Ah = SM;
  _Float16* Al = SM + 4096;
  _Float16* Bh = SM + 8192;
  _Float16* Bl = SM + 12288;
  const int w = t >> 6, l = t & 63;
  const int n16 = l & 15, q = l >> 4;
  const int bi = bx, bo = by;
  const int m0 = bi * 64 + w * 16;

  floatx4 acc[4];
#pragma unroll
  for (int ct = 0; ct < 4; ++ct) acc[ct] = (floatx4)0.f;

  for (int kc = 0; kc < 4; ++kc) {
    if (kc) __syncthreads();
#pragma unroll
    for (int p = 0; p < 4; ++p) {
      const int idx = p * 256 + t;
      const int r = idx >> 4;
      const int c4 = (idx & 15) << 2;
      const int dst = r * 64 + ((((idx & 15) >> 1)) ^ (r & 7)) * 8 + (idx & 1) * 4;
      float4 hv = *(const float4*)(H + (size_t)(bi * 64 + r) * IN_FEAT + kc * 64 + c4);
      float4 wv = *(const float4*)(Wt + (size_t)(bo * 64 + r) * IN_FEAT + kc * 64 + c4);
      union { _Float16 h[4]; int2 d; } hh_, hl_, wh_, wl_;
      hh_.h[0] = (_Float16)hv.x; hh_.h[1] = (_Float16)hv.y;
      hh_.h[2] = (_Float16)hv.z; hh_.h[3] = (_Float16)hv.w;
      hl_.h[0] = (_Float16)(hv.x - (float)hh_.h[0]);
      hl_.h[1] = (_Float16)(hv.y - (float)hh_.h[1]);
      hl_.h[2] = (_Float16)(hv.z - (float)hh_.h[2]);
      hl_.h[3] = (_Float16)(hv.w - (float)hh_.h[3]);
      wh_.h[0] = (_Float16)wv.x; wh_.h[1] = (_Float16)wv.y;
      wh_.h[2] = (_Float16)wv.z; wh_.h[3] = (_Float16)wv.w;
      wl_.h[0] = (_Float16)(wv.x - (float)wh_.h[0]);
      wl_.h[1] = (_Float16)(wv.y - (float)wh_.h[1]);
      wl_.h[2] = (_Float16)(wv.z - (float)wh_.h[2]);
      wl_.h[3] = (_Float16)(wv.w - (float)wh_.h[3]);
      *(int2*)&Ah[dst] = hh_.d;
      *(int2*)&Al[dst] = hl_.d;
      *(int2*)&Bh[dst] = wh_.d;
      *(int2*)&Bl[dst] = wl_.d;
    }
    __syncthreads();
#pragma unroll
    for (int ks = 0; ks < 2; ++ks) {
      const int ao = (w * 16 + n16) * 64 + (((ks << 2) + q) ^ (n16 & 7)) * 8;
      half8 Afh = *(const half8*)&Ah[ao];
      half8 Afl = *(const half8*)&Al[ao];
#pragma unroll
      for (int ct = 0; ct < 4; ++ct) {
        const int bofs = (ct * 16 + n16) * 64 + (((ks << 2) + q) ^ (n16 & 7)) * 8;
        half8 Bfh = *(const half8*)&Bh[bofs];
        half8 Bfl = *(const half8*)&Bl[bofs];
        acc[ct] = __builtin_amdgcn_mfma_f32_16x16x32_f16(Afh, Bfh, acc[ct], 0, 0, 0);
        acc[ct] = __builtin_amdgcn_mfma_f32_16x16x32_f16(Afl, Bfh, acc[ct], 0, 0, 0);
        acc[ct] = __builtin_amdgcn_mfma_f32_16x16x32_f16(Afh, Bfl, acc[ct], 0, 0, 0);
      }
    }
  }

  float aLv[4], aRv[4];
#pragma unroll
  for (int ct = 0; ct < 4; ++ct) {
    aLv[ct] = a[ct * 16 + n16];
    aRv[ct] = a[64 + ct * 16 + n16];
  }
#pragma unroll
  for (int reg = 0; reg < 4; ++reg) {
    float sl = 0.f, sr = 0.f;
#pragma unroll
    for (int ct = 0; ct < 4; ++ct) {
      sl = fmaf(acc[ct][reg], aLv[ct], sl);
      sr = fmaf(acc[ct][reg], aRv[ct], sr);
    }
#pragma unroll
    for (int off = 1; off < 16; off <<= 1) {
      sl += __shfl_xor(sl, off);
      sr += __shfl_xor(sr, off);
    }
    if (n16 == 0) {
      const int rowi = m0 + q * 4 + reg;
      elT[(size_t)bo * N_NODES + rowi] = sl;
      eR1h[(size_t)bo * N_NODES + rowi] = (_Float16)__expf(sr);
      eR2h[(size_t)bo * N_NODES + rowi] = (_Float16)__expf(0.2f * sr);
    }
  }

  __syncthreads();
  _Float16* LG = SM;  // 64 x 72 halfs
#pragma unroll
  for (int ct = 0; ct < 4; ++ct)
#pragma unroll
    for (int reg = 0; reg < 4; ++reg)
      LG[(w * 16 + q * 4 + reg) * 72 + ct * 16 + n16] = (_Float16)acc[ct][reg];
  __syncthreads();
  {
    const int f = t >> 2, jq = t & 3;
    union { _Float16 hh[16]; int4 v[2]; } u;
#pragma unroll
    for (int k = 0; k < 16; ++k) u.hh[k] = LG[(jq * 16 + k) * 72 + f];
    _Float16* dst = GT16 + (size_t)(bo * 64 + f) * N_NODES + bi * 64 + jq * 16;
    *(int4*)dst = u.v[0];
    *(int4*)(dst + 8) = u.v[1];
  }
}

// ---------------- dense attention v6: packed-fp16 P-gen, i-tile 32 -------
// Grid (128 i-tiles, 8 heads), 256 threads = 4 waves: wave w -> row-tile
// rt=w&1 (16 rows), j-half jh=w>>1 (2048 j). Per 64-j step:
//   pv2 = pk_max(eL1*eR1, eL2*eR2) (packed fp16; exp(lrelu(x))=max(e^x,e^.2x))
//   sel = (pv & keep) | (1.0h2 & ~keep), keep from adjacency bit-pair.
// A-frags built in registers; Z via ones-column MFMA; combine in LDS.
__global__ __launch_bounds__(256) void attn_v6(
    const unsigned long long* __restrict__ bits, const _Float16* __restrict__ GT16,
    const float* __restrict__ elT, const _Float16* __restrict__ eR1h,
    const _Float16* __restrict__ eR2h, float* __restrict__ out) {
  __shared__ __align__(16) _Float16 Gt[2][2][4096];   // [par][jh], 32 KB
  __shared__ __align__(16) _Float16 eRs1[2][2][64];   // 512 B
  __shared__ __align__(16) _Float16 eRs2[2][2][64];   // 512 B
  __shared__ uint2 bitsS[2][2][32];                   // 1 KB
  __shared__ float eL1s[32], eL2s[32];
  __shared__ float Zh1[32], Zfull[32];

  const int t = threadIdx.x;
  const int ib = blockIdx.x, h = blockIdx.y;
  const int i0 = ib * 32;
  const int w = t >> 6, l = t & 63, n16 = l & 15, q = l >> 4;
  const int rt = w & 1, jh = w >> 1;

  // staging roles
  const int gjh = t >> 7, sf = (t >> 1) & 63, hrow = t & 1;
  const _Float16* gsrc = GT16 + (size_t)(h * 64 + sf) * N_NODES + gjh * 2048 + hrow * 32;
  const int era = (t >> 3) & 1, erjh = t >> 4, erseg = t & 7;       // t<32
  const int bro = (t - 32) & 31, brjh = (t - 32) >> 5;              // 32<=t<96

  if (t < 32) {
    float e = elT[(size_t)h * N_NODES + i0 + t];
    eL1s[t] = __expf(e);
    eL2s[t] = __expf(0.2f * e);
  }
  // stage step 0 into par=0
  {
#pragma unroll
    for (int g = 0; g < 4; ++g) {
      int4 v = *(const int4*)(gsrc + g * 8);
      *(int4*)&Gt[0][gjh][sf * 64 + ((hrow * 4 + g) ^ (sf & 7)) * 8] = v;
    }
    if (t < 32) {
      const _Float16* esrc = (era ? eR2h : eR1h) + (size_t)h * N_NODES + erjh * 2048 + erseg * 8;
      int4 v = *(const int4*)esrc;
      *(int4*)&(era ? eRs2 : eRs1)[0][erjh][erseg * 8] = v;
    } else if (t < 96) {
      bitsS[0][brjh][bro] = *(const uint2*)&bits[(size_t)(i0 + bro) * 64 + brjh * 32];
    }
  }
  __syncthreads();

  const _Float16 e1f = (_Float16)eL1s[rt * 16 + n16];
  const _Float16 e2f = (_Float16)eL2s[rt * 16 + n16];
  const h2 eL1h2 = {e1f, e1f};
  const h2 eL2h2 = {e2f, e2f};
  half8 Bones;
#pragma unroll
  for (int k = 0; k < 8; ++k) Bones[k] = (n16 == 0) ? (_Float16)1.f : (_Float16)0.f;

  floatx4 acc[4];
#pragma unroll
  for (int ft = 0; ft < 4; ++ft) acc[ft] = (floatx4)0.f;
  floatx4 acc5 = (floatx4)0.f;

  int par = 0;
  for (int step = 0; step < 32; ++step) {
    // ---- issue next-step global loads into registers ----
    int4 gv[4]; int4 ev; uint2 bv2;
    const bool more = (step + 1 < 32);
    if (more) {
      const _Float16* gs = gsrc + (size_t)(step + 1) * 64;
#pragma unroll
      for (int g = 0; g < 4; ++g) gv[g] = *(const int4*)(gs + g * 8);
      if (t < 32) {
        const _Float16* esrc = (era ? eR2h : eR1h) + (size_t)h * N_NODES + erjh * 2048 +
                               (step + 1) * 64 + erseg * 8;
        ev = *(const int4*)esrc;
      } else if (t < 96) {
        bv2 = *(const uint2*)&bits[(size_t)(i0 + bro) * 64 + brjh * 32 + step + 1];
      }
    }
    // ---- compute current step ----
    const uint2 bw = bitsS[par][jh][rt * 16 + n16];
    const _Float16* gt = &Gt[par][jh][0];
#pragma unroll
    for (int ks = 0; ks < 2; ++ks) {
      const unsigned dw = ks ? bw.y : bw.x;
      const unsigned byte = (dw >> (q * 8)) & 0xffu;
      uint4 r1 = *(const uint4*)&eRs1[par][jh][ks * 32 + q * 8];
      uint4 r2 = *(const uint4*)&eRs2[par][jh][ks * 32 + q * 8];
      const unsigned r1a[4] = {r1.x, r1.y, r1.z, r1.w};
      const unsigned r2a[4] = {r2.x, r2.y, r2.z, r2.w};
      unsigned pr[4];
#pragma unroll
      for (int kk = 0; kk < 4; ++kk) {
        h2 pa = eL1h2 * __builtin_bit_cast(h2, r1a[kk]);
        h2 pb = eL2h2 * __builtin_bit_cast(h2, r2a[kk]);
        h2 pv = __builtin_elementwise_max(pa, pb);
        unsigned y = (byte >> (2 * kk)) & 3u;
        unsigned b01 = (y | (y << 15)) & 0x00010001u;
        unsigned keep = b01 * 0xffffu;
        pr[kk] = (__builtin_bit_cast(unsigned, pv) & keep) | (0x3C003C00u & ~keep);
      }
      const uint4 prv = {pr[0], pr[1], pr[2], pr[3]};
      half8 Af = __builtin_bit_cast(half8, prv);
#pragma unroll
      for (int ft = 0; ft < 4; ++ft) {
        half8 Bf = *(const half8*)&gt[(ft * 16 + n16) * 64 + (((ks << 2) + q) ^ (n16 & 7)) * 8];
        acc[ft] = __builtin_amdgcn_mfma_f32_16x16x32_f16(Af, Bf, acc[ft], 0, 0, 0);
      }
      acc5 = __builtin_amdgcn_mfma_f32_16x16x32_f16(Af, Bones, acc5, 0, 0, 0);
    }
    // ---- store staged registers into other parity ----
    if (more) {
      const int np = par ^ 1;
#pragma unroll
      for (int g = 0; g < 4; ++g)
        *(int4*)&Gt[np][gjh][sf * 64 + ((hrow * 4 + g) ^ (sf & 7)) * 8] = gv[g];
      if (t < 32) {
        *(int4*)&(era ? eRs2 : eRs1)[np][erjh][erseg * 8] = ev;
      } else if (t < 96) {
        bitsS[np][brjh][bro] = bv2;
      }
    }
    __syncthreads();
    par ^= 1;
  }

  // ---- combine j-halves, normalize, store ----
  float* comb = (float*)&Gt[0][0][0];  // 32 x 68 fp32 = 8.7 KB
  if (jh == 1) {
#pragma unroll
    for (int ft = 0; ft < 4; ++ft)
#pragma unroll
      for (int reg = 0; reg < 4; ++reg)
        comb[(rt * 16 + q * 4 + reg) * 68 + ft * 16 + n16] = acc[ft][reg];
    if (n16 == 0) {
#pragma unroll
      for (int reg = 0; reg < 4; ++reg) Zh1[rt * 16 + q * 4 + reg] = acc5[reg];
    }
  }
  __syncthreads();
  if (jh == 0) {
#pragma unroll
    for (int ft = 0; ft < 4; ++ft)
#pragma unroll
      for (int reg = 0; reg < 4; ++reg)
        acc[ft][reg] += comb[(rt * 16 + q * 4 + reg) * 68 + ft * 16 + n16];
    if (n16 == 0) {
#pragma unroll
      for (int reg = 0; reg < 4; ++reg) {
        const int row = rt * 16 + q * 4 + reg;
        Zfull[row] = acc5[reg] + Zh1[row];
      }
    }
  }
  __syncthreads();
  if (jh == 0) {
#pragma unroll
    for (int reg = 0; reg < 4; ++reg) {
      const int row = rt * 16 + q * 4 + reg;
      const float invz = 1.f / Zfull[row];
      float* op = out + (size_t)(i0 + row) * OUT_FEAT + h * 64;
#pragma unroll
      for (int ft = 0; ft < 4; ++ft) op[ft * 16 + n16] = acc[ft][reg] * invz;
    }
  }
}

extern "C" void kernel_launch(void* const* d_in, const int* in_sizes, int n_in,
                              void* d_out, int out_size, void* d_ws, size_t ws_size,
                              hipStream_t stream) {
  const float* h   = (const float*)d_in[0];
  const float* adj = (const float*)d_in[1];
  const float* W   = (const float*)d_in[2];
  const float* a   = (const float*)d_in[3];
  float* out = (float*)d_out;

  char* ws = (char*)d_ws;
  _Float16* GT16 = (_Float16*)ws;                                         // 4 MB
  unsigned long long* bits = (unsigned long long*)(ws + 4u * 1024 * 1024);// 2 MB
  float* elT = (float*)(ws + 6u * 1024 * 1024);                           // 128 KB
  _Float16* eR1h = (_Float16*)(ws + 6u * 1024 * 1024 + 128 * 1024);       // 64 KB
  _Float16* eR2h = (_Float16*)(ws + 6u * 1024 * 1024 + 192 * 1024);       // 64 KB

  produce<<<dim3(64, 16), 256, 0, stream>>>(h, adj, W, a, GT16, elT, eR1h, eR2h, bits);
  attn_v6<<<dim3(128, 8), 256, 0, stream>>>(bits, GT16, elT, eR1h, eR2h, out);
}